// Round 3
// baseline (254.202 us; speedup 1.0000x reference)
//
#include <hip/hip_runtime.h>

// Problem constants (from reference)
#define BATCH 128
#define SEQ   2000
#define EMB   50          // 25 float2 per row
#define OUTD  2

// Tiling: 2 lanes cooperate on one embedding row; each pair handles 2 rows
// (ILP=2) so a thread has up to 26 independent float2 gathers in flight.
#define CHUNKS 8                       // seq chunks per batch row
#define RPB    (SEQ / CHUNKS)          // 250 rows per block
#define PAIRS  128                     // thread pairs per block
#define TPB    256
#define WAVES  (TPB / 64)

__global__ __launch_bounds__(TPB) void embbag_partial_kernel(
    const int* __restrict__ t,          // [BATCH, SEQ]
    const float* __restrict__ emb,      // [VOCAB, EMB]
    const float* __restrict__ W,        // [OUTD, EMB]
    float* __restrict__ partial)        // [BATCH, CHUNKS, OUTD]
{
    // wl[i] = (W0[2i], W0[2i+1], W1[2i], W1[2i+1]) for float2 element i
    __shared__ float4 wl[EMB / 2];
    __shared__ float2 red[WAVES];

    const int tid = threadIdx.x;
    const int c = blockIdx.x;
    const int b = blockIdx.y;

    if (tid < EMB / 2) {
        wl[tid] = make_float4(W[2 * tid], W[2 * tid + 1],
                              W[EMB + 2 * tid], W[EMB + 2 * tid + 1]);
    }
    __syncthreads();

    const int pair = tid >> 1;          // 0..127
    const int k    = tid & 1;           // lane-within-pair

    // Row A: always valid (pair < 128 <= RPB). Row B: pair+128 may exceed RPB.
    const int sA = c * RPB + pair;
    const int sB = sA + PAIRS;
    const int idxA = t[b * SEQ + sA];
    const bool haveB = (pair + PAIRS) < RPB;
    const int idxB = haveB ? t[b * SEQ + sB] : -1;

    // Unconditional gathers via safe index + mask multiply (no divergence).
    const float mA = (idxA != -1) ? 1.0f : 0.0f;
    const float mB = (idxB != -1) ? 1.0f : 0.0f;
    const float2* __restrict__ rowA =
        (const float2*)(emb + (size_t)(idxA != -1 ? idxA : 0) * EMB);
    const float2* __restrict__ rowB =
        (const float2*)(emb + (size_t)(idxB != -1 ? idxB : 0) * EMB);

    float a0A = 0.0f, a1A = 0.0f, a0B = 0.0f, a1B = 0.0f;
#pragma unroll
    for (int i = 0; i < 12; ++i) {
        float2 eA = rowA[2 * i + k];
        float2 eB = rowB[2 * i + k];
        float4 w = wl[2 * i + k];
        a0A = fmaf(eA.x, w.x, fmaf(eA.y, w.y, a0A));
        a1A = fmaf(eA.x, w.z, fmaf(eA.y, w.w, a1A));
        a0B = fmaf(eB.x, w.x, fmaf(eB.y, w.y, a0B));
        a1B = fmaf(eB.x, w.z, fmaf(eB.y, w.w, a1B));
    }
    if (k == 0) {                       // odd tail: float2 element 24
        float2 eA = rowA[24];
        float2 eB = rowB[24];
        float4 w = wl[24];
        a0A = fmaf(eA.x, w.x, fmaf(eA.y, w.y, a0A));
        a1A = fmaf(eA.x, w.z, fmaf(eA.y, w.w, a1A));
        a0B = fmaf(eB.x, w.x, fmaf(eB.y, w.y, a0B));
        a1B = fmaf(eB.x, w.z, fmaf(eB.y, w.w, a1B));
    }
    float a0 = mA * a0A + mB * a0B;
    float a1 = mA * a1A + mB * a1B;

    // wave (64-lane) shuffle reduction — sums pair halves too
#pragma unroll
    for (int off = 32; off > 0; off >>= 1) {
        a0 += __shfl_down(a0, off, 64);
        a1 += __shfl_down(a1, off, 64);
    }
    const int wave = tid >> 6;
    const int lane = tid & 63;
    if (lane == 0) red[wave] = make_float2(a0, a1);
    __syncthreads();

    if (tid == 0) {
        float s0 = 0.0f, s1 = 0.0f;
#pragma unroll
        for (int w = 0; w < WAVES; ++w) { s0 += red[w].x; s1 += red[w].y; }
        float* p = partial + ((size_t)b * CHUNKS + c) * OUTD;
        p[0] = s0;
        p[1] = s1;
    }
}

// Kernel 2: one (b,o) pair per thread: sum CHUNKS partials, /BATCH, +bias, relu.
__global__ __launch_bounds__(TPB) void finalize_kernel(
    const float* __restrict__ partial,  // [BATCH, CHUNKS, OUTD]
    const float* __restrict__ bias,     // [OUTD]
    float* __restrict__ out)            // [BATCH, OUTD]
{
    const int i = threadIdx.x;
    if (i < BATCH * OUTD) {
        const int b = i >> 1;
        const int o = i & 1;
        float s = 0.0f;
#pragma unroll
        for (int c = 0; c < CHUNKS; ++c)
            s += partial[((size_t)b * CHUNKS + c) * OUTD + o];
        s = s * (1.0f / (float)BATCH) + bias[o];
        out[i] = fmaxf(s, 0.0f);
    }
}

extern "C" void kernel_launch(void* const* d_in, const int* in_sizes, int n_in,
                              void* d_out, int out_size, void* d_ws, size_t ws_size,
                              hipStream_t stream) {
    const int*   t    = (const int*)d_in[0];
    const float* emb  = (const float*)d_in[1];
    const float* W    = (const float*)d_in[2];
    const float* bias = (const float*)d_in[3];
    float* out        = (float*)d_out;
    float* partial    = (float*)d_ws;   // BATCH*CHUNKS*OUTD floats = 8 KB

    dim3 grid(CHUNKS, BATCH);
    embbag_partial_kernel<<<grid, TPB, 0, stream>>>(t, emb, W, partial);
    finalize_kernel<<<1, TPB, 0, stream>>>(partial, bias, out);
}